// Round 1
// baseline (346.353 us; speedup 1.0000x reference)
//
#include <hip/hip_runtime.h>
#include <hip/hip_bf16.h>

// GraphSAGEConv: N=50000 nodes, E=800000 edges, D=64 in/out, fp32.
// out = x @ W_self^T + b_self + (scatter_mean(x[col] -> row)) @ W_neigh^T + b_neigh
//
// ws layout: [agg: N*64 f32][deg: N f32][flag: 1 int]  (~13 MB)

#define D 64

// ---- runtime edge_index dtype detection ------------------------------------
// Reference dtype is int64 but harness may deliver int32. Reading int32 data
// as int64 yields values >= N unless the high half happens to be 0 (p~1/N).
__global__ void detect_k(const long long* __restrict__ ei, int* __restrict__ flag, int n) {
    if (threadIdx.x == 0 && blockIdx.x == 0) {
        int is64 = 1;
        for (int i = 0; i < 16; ++i) {
            long long v = ei[i];
            if (v < 0 || v >= (long long)n) { is64 = 0; break; }
        }
        *flag = is64;
    }
}

__device__ __forceinline__ int load_idx(const void* ei, int use64, int pos) {
    if (use64) return (int)((const long long*)ei)[pos];
    return ((const int*)ei)[pos];
}

// ---- scatter: one wave per edge, lane = feature ----------------------------
__global__ __launch_bounds__(256) void scatter_k(
        const float* __restrict__ x, const void* __restrict__ ei,
        const int* __restrict__ flag,
        float* __restrict__ agg, float* __restrict__ deg, int E) {
    long long tid = (long long)blockIdx.x * 256 + threadIdx.x;
    int e = (int)(tid >> 6);
    int f = (int)(tid & 63);
    if (e >= E) return;
    int use64 = *flag;                       // scalar, cached
    int r = load_idx(ei, use64, e);          // row = destination
    int c = load_idx(ei, use64, E + e);      // col = source
    atomicAdd(&agg[r * D + f], x[c * D + f]);
    if (f == 0) atomicAdd(&deg[r], 1.0f);
}

// ---- epilogue: wave per node, lane = output feature ------------------------
#define NPB 4   // nodes (waves) per 256-thread block
__global__ __launch_bounds__(256) void out_k(
        const float* __restrict__ x, const float* __restrict__ agg,
        const float* __restrict__ deg,
        const float* __restrict__ Ws, const float* __restrict__ bs,
        const float* __restrict__ Wn, const float* __restrict__ bn,
        float* __restrict__ out, int N) {
    __shared__ float sWs[D][D + 1];   // +1 pad: stride 65 -> (f+k)%32 banks, 2-way = free
    __shared__ float sWn[D][D + 1];
    __shared__ float sx[NPB][D];
    __shared__ float sm[NPB][D];

    int t = threadIdx.x;
    for (int i = t; i < D * D; i += 256) {
        sWs[i >> 6][i & 63] = Ws[i];
        sWn[i >> 6][i & 63] = Wn[i];
    }

    int w = t >> 6;       // wave id within block
    int f = t & 63;       // lane = output feature
    int n = blockIdx.x * NPB + w;
    if (n < N) {
        float d = deg[n];
        d = d > 1.0f ? d : 1.0f;
        sx[w][f] = x[n * D + f];
        sm[w][f] = agg[n * D + f] / d;
    }
    __syncthreads();
    if (n >= N) return;

    float acc = bs[f] + bn[f];
#pragma unroll
    for (int k = 0; k < D; ++k) {
        acc += sWs[f][k] * sx[w][k] + sWn[f][k] * sm[w][k];
    }
    out[n * D + f] = acc;
}

extern "C" void kernel_launch(void* const* d_in, const int* in_sizes, int n_in,
                              void* d_out, int out_size, void* d_ws, size_t ws_size,
                              hipStream_t stream) {
    const float* x  = (const float*)d_in[0];
    const void*  ei = d_in[1];
    const float* Ws = (const float*)d_in[2];
    const float* bs = (const float*)d_in[3];
    const float* Wn = (const float*)d_in[4];
    const float* bn = (const float*)d_in[5];

    int N = in_sizes[0] / D;
    int E = in_sizes[1] / 2;

    float* agg  = (float*)d_ws;
    float* deg  = agg + (size_t)N * D;
    int*   flag = (int*)(deg + N);

    // zero agg + deg + flag
    hipMemsetAsync(d_ws, 0, (size_t)N * (D + 1) * sizeof(float) + sizeof(int), stream);

    detect_k<<<1, 1, 0, stream>>>((const long long*)ei, flag, N);

    long long total = (long long)E * D;
    int sblocks = (int)((total + 255) / 256);
    scatter_k<<<sblocks, 256, 0, stream>>>(x, ei, flag, agg, deg, E);

    out_k<<<(N + NPB - 1) / NPB, 256, 0, stream>>>(x, agg, deg, Ws, bs, Wn, bn,
                                                   (float*)d_out, N);
}

// Round 2
// 322.424 us; speedup vs baseline: 1.0742x; 1.0742x over previous
//
#include <hip/hip_runtime.h>
#include <hip/hip_bf16.h>

// GraphSAGEConv: N=50000 nodes, E=800000 edges, D=64 in/out, fp32.
// out = x @ W_self^T + b_self + scatter_mean(x[col] -> row) @ W_neigh^T + b_neigh
//
// Strategy: counting-sort edges by destination (CSR), then wave-per-node
// gather+mean fused directly with the two 64x64 linears. No fp32 atomics,
// no agg materialization.
//
// ws layout: [cnt: N int][cursor: N int][off: N+1 int][sorted: E int][flag: 1 int]

#define D 64

// ---- runtime edge_index dtype detection ------------------------------------
__global__ void detect_k(const long long* __restrict__ ei, int* __restrict__ flag, int n) {
    if (threadIdx.x == 0 && blockIdx.x == 0) {
        int is64 = 1;
        for (int i = 0; i < 16; ++i) {
            long long v = ei[i];
            if (v < 0 || v >= (long long)n) { is64 = 0; break; }
        }
        *flag = is64;
    }
}

__device__ __forceinline__ int load_idx(const void* ei, int use64, long long pos) {
    if (use64) return (int)((const long long*)ei)[pos];
    return ((const int*)ei)[pos];
}

// ---- histogram of destination (row) ----------------------------------------
__global__ __launch_bounds__(256) void hist_k(
        const void* __restrict__ ei, const int* __restrict__ flag,
        int* __restrict__ cnt, int E) {
    int e = blockIdx.x * 256 + threadIdx.x;
    if (e >= E) return;
    int use64 = *flag;
    int r = load_idx(ei, use64, e);
    atomicAdd(&cnt[r], 1);
}

// ---- single-block exclusive scan of cnt[N] -> off[N+1] ---------------------
__global__ __launch_bounds__(1024) void scan_k(
        const int* __restrict__ cnt, int* __restrict__ off, int N) {
    __shared__ int buf[1024];
    int t = threadIdx.x;
    int C = (N + 1023) >> 10;             // elements per thread
    int lo = t * C;
    int hi = lo + C; if (hi > N) hi = N;
    if (lo > N) lo = N;
    int s = 0;
    for (int i = lo; i < hi; ++i) s += cnt[i];
    buf[t] = s;
    __syncthreads();
    // Hillis-Steele inclusive scan over 1024 partials
    for (int ofs = 1; ofs < 1024; ofs <<= 1) {
        int add = (t >= ofs) ? buf[t - ofs] : 0;
        __syncthreads();
        buf[t] += add;
        __syncthreads();
    }
    int run = buf[t] - s;                 // exclusive prefix for this chunk
    for (int i = lo; i < hi; ++i) { off[i] = run; run += cnt[i]; }
    if (t == 1023) off[N] = buf[1023];
}

// ---- scatter col indices into CSR order ------------------------------------
__global__ __launch_bounds__(256) void scatter_edges_k(
        const void* __restrict__ ei, const int* __restrict__ flag,
        const int* __restrict__ off, int* __restrict__ cursor,
        int* __restrict__ sorted, int E) {
    int e = blockIdx.x * 256 + threadIdx.x;
    if (e >= E) return;
    int use64 = *flag;
    int r = load_idx(ei, use64, e);
    int c = load_idx(ei, use64, (long long)E + e);
    int p = atomicAdd(&cursor[r], 1);
    sorted[off[r] + p] = c;
}

// ---- fused gather-mean + dual linear ---------------------------------------
#define NPB 4   // waves (nodes) per 256-thread block
__global__ __launch_bounds__(256) void fused_k(
        const float* __restrict__ x,
        const int* __restrict__ off, const int* __restrict__ sorted,
        const float* __restrict__ Ws, const float* __restrict__ bs,
        const float* __restrict__ Wn, const float* __restrict__ bn,
        float* __restrict__ out, int N) {
    __shared__ float sWs[D][D + 1];   // +1 pad: 2-way bank alias = free on CDNA4
    __shared__ float sWn[D][D + 1];
    __shared__ float sx[NPB][D];
    __shared__ float sm[NPB][D];

    int t = threadIdx.x;
    for (int i = t; i < D * D; i += 256) {
        sWs[i >> 6][i & 63] = Ws[i];
        sWn[i >> 6][i & 63] = Wn[i];
    }

    int w = t >> 6;       // wave id within block
    int f = t & 63;       // lane = feature
    int n = blockIdx.x * NPB + w;
    if (n < N) {
        int a = off[n], b = off[n + 1];
        float s = 0.0f;
        int j = a;
        for (; j + 3 < b; j += 4) {       // 4-way ILP on the gather
            int c0 = sorted[j], c1 = sorted[j + 1];
            int c2 = sorted[j + 2], c3 = sorted[j + 3];
            s += x[(size_t)c0 * D + f] + x[(size_t)c1 * D + f]
               + x[(size_t)c2 * D + f] + x[(size_t)c3 * D + f];
        }
        for (; j < b; ++j) s += x[(size_t)sorted[j] * D + f];
        float d = (float)(b - a);
        if (d < 1.0f) d = 1.0f;
        sm[w][f] = s / d;
        sx[w][f] = x[(size_t)n * D + f];
    }
    __syncthreads();
    if (n >= N) return;

    float acc = bs[f] + bn[f];
#pragma unroll
    for (int k = 0; k < D; ++k) {
        acc += sWs[f][k] * sx[w][k] + sWn[f][k] * sm[w][k];
    }
    out[(size_t)n * D + f] = acc;
}

extern "C" void kernel_launch(void* const* d_in, const int* in_sizes, int n_in,
                              void* d_out, int out_size, void* d_ws, size_t ws_size,
                              hipStream_t stream) {
    const float* x  = (const float*)d_in[0];
    const void*  ei = d_in[1];
    const float* Ws = (const float*)d_in[2];
    const float* bs = (const float*)d_in[3];
    const float* Wn = (const float*)d_in[4];
    const float* bn = (const float*)d_in[5];

    int N = in_sizes[0] / D;
    int E = in_sizes[1] / 2;

    int* cnt    = (int*)d_ws;
    int* cursor = cnt + N;
    int* off    = cursor + N;
    int* sorted = off + N + 1;
    int* flag   = sorted + E;

    // zero cnt + cursor
    hipMemsetAsync(d_ws, 0, (size_t)2 * N * sizeof(int), stream);

    detect_k<<<1, 1, 0, stream>>>((const long long*)ei, flag, N);

    int eb = (E + 255) / 256;
    hist_k<<<eb, 256, 0, stream>>>(ei, flag, cnt, E);
    scan_k<<<1, 1024, 0, stream>>>(cnt, off, N);
    scatter_edges_k<<<eb, 256, 0, stream>>>(ei, flag, off, cursor, sorted, E);

    fused_k<<<(N + NPB - 1) / NPB, 256, 0, stream>>>(x, off, sorted,
                                                     Ws, bs, Wn, bn,
                                                     (float*)d_out, N);
}

// Round 4
// 291.682 us; speedup vs baseline: 1.1874x; 1.1054x over previous
//
#include <hip/hip_runtime.h>
#include <hip/hip_bf16.h>

// GraphSAGEConv: N=50000 nodes, E=800000 edges, D=64 in/out, fp32.
// out = x @ W_self^T + b_self + scatter_mean(x[col] -> row) @ W_neigh^T + b_neigh
//
// CSR counting-sort (R2-proven build) + occupancy-tuned fused gather/linear.
// ws layout: [cnt: N int][cursor: N int][off: N+1 int][sorted: E int][flag: 1 int]

#define D 64
#define NPB 8      // nodes (waves) per 512-thread block in fused_k

// ---- runtime edge_index dtype detection ------------------------------------
// Reference dtype is int64 but harness may deliver int32. int32 data read as
// int64 gives values out of [0,N) with overwhelming probability.
__global__ void detect_k(const long long* __restrict__ ei, int* __restrict__ flag, int n) {
    if (threadIdx.x == 0 && blockIdx.x == 0) {
        int is64 = 1;
        for (int i = 0; i < 16; ++i) {
            long long v = ei[i];
            if (v < 0 || v >= (long long)n) { is64 = 0; break; }
        }
        *flag = is64;
    }
}

__device__ __forceinline__ int load_idx(const void* ei, int use64, long long pos) {
    if (use64) return (int)((const long long*)ei)[pos];
    return ((const int*)ei)[pos];
}

// ---- histogram of destination (row) ----------------------------------------
__global__ __launch_bounds__(256) void hist_k(
        const void* __restrict__ ei, const int* __restrict__ flag,
        int* __restrict__ cnt, int E) {
    int e = blockIdx.x * 256 + threadIdx.x;
    if (e >= E) return;
    int use64 = *flag;
    int r = load_idx(ei, use64, e);
    atomicAdd(&cnt[r], 1);
}

// ---- single-block exclusive scan of cnt[N] -> off[N+1] ---------------------
__global__ __launch_bounds__(1024) void scan_k(
        const int* __restrict__ cnt, int* __restrict__ off, int N) {
    __shared__ int buf[1024];
    int t = threadIdx.x;
    int C = (N + 1023) >> 10;             // elements per thread
    int lo = t * C;
    int hi = lo + C; if (hi > N) hi = N;
    if (lo > N) lo = N;
    int s = 0;
    for (int i = lo; i < hi; ++i) s += cnt[i];
    buf[t] = s;
    __syncthreads();
    // Hillis-Steele inclusive scan over 1024 partials
    for (int ofs = 1; ofs < 1024; ofs <<= 1) {
        int add = (t >= ofs) ? buf[t - ofs] : 0;
        __syncthreads();
        buf[t] += add;
        __syncthreads();
    }
    int run = buf[t] - s;                 // exclusive prefix for this chunk
    for (int i = lo; i < hi; ++i) { off[i] = run; run += cnt[i]; }
    if (t == 1023) off[N] = buf[1023];
}

// ---- scatter col indices into CSR order ------------------------------------
__global__ __launch_bounds__(256) void scatter_edges_k(
        const void* __restrict__ ei, const int* __restrict__ flag,
        const int* __restrict__ off, int* __restrict__ cursor,
        int* __restrict__ sorted, int E) {
    int e = blockIdx.x * 256 + threadIdx.x;
    if (e >= E) return;
    int use64 = *flag;
    int r = load_idx(ei, use64, e);
    int c = load_idx(ei, use64, (long long)E + e);
    int p = atomicAdd(&cursor[r], 1);
    sorted[off[r] + p] = c;
}

// ---- fused gather-mean + dual linear ---------------------------------------
// 512 threads, 8 nodes/block: LDS 37.4 KB -> 4 blocks/CU x 8 waves = 32/32
// waves per CU (R2 was 16/32). Neighbor indices loaded coalesced (64/row)
// and broadcast via __shfl.
__global__ __launch_bounds__(512, 8) void fused_k(
        const float* __restrict__ x,
        const int* __restrict__ off, const int* __restrict__ sorted,
        const float* __restrict__ Ws, const float* __restrict__ bs,
        const float* __restrict__ Wn, const float* __restrict__ bn,
        float* __restrict__ out, int N) {
    __shared__ float sWs[D][D + 1];   // stride 65 -> 2-way bank alias = free
    __shared__ float sWn[D][D + 1];
    __shared__ float sx[NPB][D];
    __shared__ float sm[NPB][D];

    int t = threadIdx.x;
    for (int i = t; i < D * D; i += 512) {
        sWs[i >> 6][i & 63] = Ws[i];
        sWn[i >> 6][i & 63] = Wn[i];
    }

    int w = t >> 6;       // wave id within block
    int f = t & 63;       // lane = feature
    int n = blockIdx.x * NPB + w;
    if (n < N) {
        int a = off[n], b = off[n + 1];
        float s = 0.0f;
        for (int base = a; base < b; base += 64) {
            int rem = b - base;
            int cl = (f < rem) ? sorted[base + f] : 0;   // coalesced idx load
            int m = rem < 64 ? rem : 64;
            int j = 0;
            for (; j + 3 < m; j += 4) {
                int c0 = __shfl(cl, j),     c1 = __shfl(cl, j + 1);
                int c2 = __shfl(cl, j + 2), c3 = __shfl(cl, j + 3);
                float v0 = x[c0 * D + f], v1 = x[c1 * D + f];
                float v2 = x[c2 * D + f], v3 = x[c3 * D + f];
                s += (v0 + v1) + (v2 + v3);
            }
            for (; j < m; ++j) {
                int c = __shfl(cl, j);
                s += x[c * D + f];
            }
        }
        int deg = b - a;
        float dinv = (deg > 0) ? 1.0f / (float)deg : 0.0f;
        sm[w][f] = s * dinv;
        sx[w][f] = x[n * D + f];
    }
    __syncthreads();
    if (n >= N) return;

    float acc = bs[f] + bn[f];
#pragma unroll
    for (int k = 0; k < D; ++k) {
        acc += sWs[f][k] * sx[w][k] + sWn[f][k] * sm[w][k];
    }
    out[n * D + f] = acc;
}

extern "C" void kernel_launch(void* const* d_in, const int* in_sizes, int n_in,
                              void* d_out, int out_size, void* d_ws, size_t ws_size,
                              hipStream_t stream) {
    const float* x  = (const float*)d_in[0];
    const void*  ei = d_in[1];
    const float* Ws = (const float*)d_in[2];
    const float* bs = (const float*)d_in[3];
    const float* Wn = (const float*)d_in[4];
    const float* bn = (const float*)d_in[5];

    int N = in_sizes[0] / D;
    int E = in_sizes[1] / 2;

    int* cnt    = (int*)d_ws;
    int* cursor = cnt + N;
    int* off    = cursor + N;
    int* sorted = off + N + 1;
    int* flag   = sorted + E;

    // zero cnt + cursor
    hipMemsetAsync(d_ws, 0, (size_t)2 * N * sizeof(int), stream);

    detect_k<<<1, 1, 0, stream>>>((const long long*)ei, flag, N);

    int eb = (E + 255) / 256;
    hist_k<<<eb, 256, 0, stream>>>(ei, flag, cnt, E);
    scan_k<<<1, 1024, 0, stream>>>(cnt, off, N);
    scatter_edges_k<<<eb, 256, 0, stream>>>(ei, flag, off, cursor, sorted, E);

    fused_k<<<(N + NPB - 1) / NPB, 512, 0, stream>>>(x, off, sorted,
                                                     Ws, bs, Wn, bn,
                                                     (float*)d_out, N);
}

// Round 5
// 226.798 us; speedup vs baseline: 1.5271x; 1.2861x over previous
//
#include <hip/hip_runtime.h>
#include <hip/hip_bf16.h>

// GraphSAGEConv: N=50000 nodes, E=800000 edges, D=64 in/out, fp32.
// out = x @ W_self^T + b_self + scatter_mean(x[col] -> row) @ W_neigh^T + b_neigh
//
// CSR counting-sort + fused gather-mean-dual-linear.
// Multi-block coalesced scan (R4's single-block scan_k was 76 us at 0.14% occ).
// Global offset of node n = off[n] + boff[n>>8]  (no third scan pass).
//
// ws layout: [cnt: N][cursor: N][off: N+1][bsum: NB][boff: NB][sorted: E][flag: 1]
// (all int; NB = ceil(N/256) = 196, requires NB <= 256 i.e. N <= 65536)

#define D 64
#define NPB 8      // nodes (waves) per 512-thread block in fused_k

// ---- runtime edge_index dtype detection (parallel probes) ------------------
// Reference dtype is int64 but harness may deliver int32. int32 data read as
// int64 gives values out of [0,N) with overwhelming probability (16 probes).
__global__ void detect_k(const long long* __restrict__ ei, int* __restrict__ flag, int n) {
    int t = threadIdx.x;
    long long v = (t < 16) ? ei[t] : 0;
    unsigned long long bad = __ballot(t < 16 && (v < 0 || v >= (long long)n));
    if (t == 0) *flag = (bad == 0ULL) ? 1 : 0;
}

__device__ __forceinline__ int load_idx(const void* ei, int use64, long long pos) {
    if (use64) return (int)((const long long*)ei)[pos];
    return ((const int*)ei)[pos];
}

// ---- histogram of destination (row) ----------------------------------------
__global__ __launch_bounds__(256) void hist_k(
        const void* __restrict__ ei, const int* __restrict__ flag,
        int* __restrict__ cnt, int E) {
    int e = blockIdx.x * 256 + threadIdx.x;
    if (e >= E) return;
    int use64 = *flag;
    int r = load_idx(ei, use64, e);
    atomicAdd(&cnt[r], 1);
}

// ---- 256-thread block exclusive scan helper --------------------------------
__device__ __forceinline__ int block_scan_excl(int v, int t, int* total) {
    __shared__ int wsum_s[4];
    int lane = t & 63, wid = t >> 6;
    int sc = v;                       // wave-inclusive scan via shuffles
    #pragma unroll
    for (int o = 1; o < 64; o <<= 1) {
        int u = __shfl_up(sc, o);
        if (lane >= o) sc += u;
    }
    if (lane == 63) wsum_s[wid] = sc;
    __syncthreads();
    int woff = 0, tot = 0;
    #pragma unroll
    for (int ww = 0; ww < 4; ++ww) {
        int s = wsum_s[ww];
        woff += (ww < wid) ? s : 0;
        tot += s;
    }
    *total = tot;
    return woff + sc - v;             // exclusive prefix
}

// ---- phase 1: per-block exclusive scan, coalesced --------------------------
__global__ __launch_bounds__(256) void scan1_k(
        const int* __restrict__ cnt, int* __restrict__ off,
        int* __restrict__ bsum, int N) {
    int t = threadIdx.x;
    int i = blockIdx.x * 256 + t;
    int v = (i < N) ? cnt[i] : 0;
    int total;
    int ex = block_scan_excl(v, t, &total);
    if (i <= N) off[i] = ex;
    if (t == 0) bsum[blockIdx.x] = total;
}

// ---- phase 2: scan the block totals (NB <= 256) ----------------------------
__global__ __launch_bounds__(256) void scan2_k(
        const int* __restrict__ bsum, int* __restrict__ boff, int NB) {
    int t = threadIdx.x;
    int v = (t < NB) ? bsum[t] : 0;
    int total;
    int ex = block_scan_excl(v, t, &total);
    if (t < NB) boff[t] = ex;
}

// ---- scatter col indices into CSR order ------------------------------------
__global__ __launch_bounds__(256) void scatter_edges_k(
        const void* __restrict__ ei, const int* __restrict__ flag,
        const int* __restrict__ off, const int* __restrict__ boff,
        int* __restrict__ cursor, int* __restrict__ sorted, int E) {
    int e = blockIdx.x * 256 + threadIdx.x;
    if (e >= E) return;
    int use64 = *flag;
    int r = load_idx(ei, use64, e);
    int c = load_idx(ei, use64, (long long)E + e);
    int p = atomicAdd(&cursor[r], 1);
    sorted[off[r] + boff[r >> 8] + p] = c;
}

// ---- fused gather-mean + dual linear ---------------------------------------
// 512 threads, 8 nodes/block: LDS 37.4 KB -> 4 blocks/CU x 8 waves = 32/32.
__global__ __launch_bounds__(512, 8) void fused_k(
        const float* __restrict__ x,
        const int* __restrict__ off, const int* __restrict__ boff,
        const int* __restrict__ sorted,
        const float* __restrict__ Ws, const float* __restrict__ bs,
        const float* __restrict__ Wn, const float* __restrict__ bn,
        float* __restrict__ out, int N) {
    __shared__ float sWs[D][D + 1];   // stride 65 -> 2-way bank alias = free
    __shared__ float sWn[D][D + 1];
    __shared__ float sx[NPB][D];
    __shared__ float sm[NPB][D];

    int t = threadIdx.x;
    for (int i = t; i < D * D; i += 512) {
        sWs[i >> 6][i & 63] = Ws[i];
        sWn[i >> 6][i & 63] = Wn[i];
    }

    int w = t >> 6;       // wave id within block
    int f = t & 63;       // lane = feature
    int n = blockIdx.x * NPB + w;
    if (n < N) {
        int a = off[n] + boff[n >> 8];
        int b = off[n + 1] + boff[(n + 1) >> 8];
        float s = 0.0f;
        for (int base = a; base < b; base += 64) {
            int rem = b - base;
            int cl = (f < rem) ? sorted[base + f] : 0;   // coalesced idx load
            int m = rem < 64 ? rem : 64;
            int j = 0;
            for (; j + 3 < m; j += 4) {
                int c0 = __shfl(cl, j),     c1 = __shfl(cl, j + 1);
                int c2 = __shfl(cl, j + 2), c3 = __shfl(cl, j + 3);
                float v0 = x[c0 * D + f], v1 = x[c1 * D + f];
                float v2 = x[c2 * D + f], v3 = x[c3 * D + f];
                s += (v0 + v1) + (v2 + v3);
            }
            for (; j < m; ++j) {
                int c = __shfl(cl, j);
                s += x[c * D + f];
            }
        }
        int deg = b - a;
        float dinv = (deg > 0) ? 1.0f / (float)deg : 0.0f;
        sm[w][f] = s * dinv;
        sx[w][f] = x[n * D + f];
    }
    __syncthreads();
    if (n >= N) return;

    float acc = bs[f] + bn[f];
#pragma unroll
    for (int k = 0; k < D; ++k) {
        acc += sWs[f][k] * sx[w][k] + sWn[f][k] * sm[w][k];
    }
    out[n * D + f] = acc;
}

extern "C" void kernel_launch(void* const* d_in, const int* in_sizes, int n_in,
                              void* d_out, int out_size, void* d_ws, size_t ws_size,
                              hipStream_t stream) {
    const float* x  = (const float*)d_in[0];
    const void*  ei = d_in[1];
    const float* Ws = (const float*)d_in[2];
    const float* bs = (const float*)d_in[3];
    const float* Wn = (const float*)d_in[4];
    const float* bn = (const float*)d_in[5];

    int N = in_sizes[0] / D;
    int E = in_sizes[1] / 2;
    int NB = (N + 255) / 256;   // 196 for N=50000; must be <= 256

    int* cnt    = (int*)d_ws;
    int* cursor = cnt + N;
    int* off    = cursor + N;
    int* bsum   = off + N + 1;
    int* boff   = bsum + NB;
    int* sorted = boff + NB;
    int* flag   = sorted + E;

    // zero cnt + cursor
    hipMemsetAsync(d_ws, 0, (size_t)2 * N * sizeof(int), stream);

    detect_k<<<1, 64, 0, stream>>>((const long long*)ei, flag, N);

    int eb = (E + 255) / 256;
    hist_k<<<eb, 256, 0, stream>>>(ei, flag, cnt, E);
    scan1_k<<<NB, 256, 0, stream>>>(cnt, off, bsum, N);
    scan2_k<<<1, 256, 0, stream>>>(bsum, boff, NB);
    scatter_edges_k<<<eb, 256, 0, stream>>>(ei, flag, off, boff, cursor, sorted, E);

    fused_k<<<(N + NPB - 1) / NPB, 512, 0, stream>>>(x, off, boff, sorted,
                                                     Ws, bs, Wn, bn,
                                                     (float*)d_out, N);
}

// Round 6
// 224.778 us; speedup vs baseline: 1.5409x; 1.0090x over previous
//
#include <hip/hip_runtime.h>
#include <hip/hip_bf16.h>

// GraphSAGEConv: N=50000 nodes, E=800000 edges, D=64 in/out, fp32.
// out = x @ W_self^T + b_self + scatter_mean(x[col] -> row) @ W_neigh^T + b_neigh
//
// CSR counting-sort (R5-proven build, unchanged) + float4 quarter-wave gather:
// each quarter-wave (16 lanes) owns one edge, each lane loads float4 (16B) of
// the neighbor row -> 4 edges per wave-instruction, 1 shfl per 4 edges.
//
// ws layout: [cnt: N][cursor: N][off: N+1][bsum: NB][boff: NB][sorted: E][flag: 1]

#define D 64
#define NPB 8      // nodes (waves) per 512-thread block in fused_k

// ---- runtime edge_index dtype detection (parallel probes) ------------------
__global__ void detect_k(const long long* __restrict__ ei, int* __restrict__ flag, int n) {
    int t = threadIdx.x;
    long long v = (t < 16) ? ei[t] : 0;
    unsigned long long bad = __ballot(t < 16 && (v < 0 || v >= (long long)n));
    if (t == 0) *flag = (bad == 0ULL) ? 1 : 0;
}

__device__ __forceinline__ int load_idx(const void* ei, int use64, long long pos) {
    if (use64) return (int)((const long long*)ei)[pos];
    return ((const int*)ei)[pos];
}

// ---- histogram of destination (row) ----------------------------------------
__global__ __launch_bounds__(256) void hist_k(
        const void* __restrict__ ei, const int* __restrict__ flag,
        int* __restrict__ cnt, int E) {
    int e = blockIdx.x * 256 + threadIdx.x;
    if (e >= E) return;
    int use64 = *flag;
    int r = load_idx(ei, use64, e);
    atomicAdd(&cnt[r], 1);
}

// ---- 256-thread block exclusive scan helper --------------------------------
__device__ __forceinline__ int block_scan_excl(int v, int t, int* total) {
    __shared__ int wsum_s[4];
    int lane = t & 63, wid = t >> 6;
    int sc = v;
    #pragma unroll
    for (int o = 1; o < 64; o <<= 1) {
        int u = __shfl_up(sc, o);
        if (lane >= o) sc += u;
    }
    if (lane == 63) wsum_s[wid] = sc;
    __syncthreads();
    int woff = 0, tot = 0;
    #pragma unroll
    for (int ww = 0; ww < 4; ++ww) {
        int s = wsum_s[ww];
        woff += (ww < wid) ? s : 0;
        tot += s;
    }
    *total = tot;
    return woff + sc - v;
}

// ---- phase 1: per-block exclusive scan, coalesced --------------------------
__global__ __launch_bounds__(256) void scan1_k(
        const int* __restrict__ cnt, int* __restrict__ off,
        int* __restrict__ bsum, int N) {
    int t = threadIdx.x;
    int i = blockIdx.x * 256 + t;
    int v = (i < N) ? cnt[i] : 0;
    int total;
    int ex = block_scan_excl(v, t, &total);
    if (i <= N) off[i] = ex;
    if (t == 0) bsum[blockIdx.x] = total;
}

// ---- phase 2: scan the block totals (NB <= 256) ----------------------------
__global__ __launch_bounds__(256) void scan2_k(
        const int* __restrict__ bsum, int* __restrict__ boff, int NB) {
    int t = threadIdx.x;
    int v = (t < NB) ? bsum[t] : 0;
    int total;
    int ex = block_scan_excl(v, t, &total);
    if (t < NB) boff[t] = ex;
}

// ---- scatter col indices into CSR order ------------------------------------
__global__ __launch_bounds__(256) void scatter_edges_k(
        const void* __restrict__ ei, const int* __restrict__ flag,
        const int* __restrict__ off, const int* __restrict__ boff,
        int* __restrict__ cursor, int* __restrict__ sorted, int E) {
    int e = blockIdx.x * 256 + threadIdx.x;
    if (e >= E) return;
    int use64 = *flag;
    int r = load_idx(ei, use64, e);
    int c = load_idx(ei, use64, (long long)E + e);
    int p = atomicAdd(&cursor[r], 1);
    sorted[off[r] + boff[r >> 8] + p] = c;
}

// ---- fused gather-mean + dual linear ---------------------------------------
// Quarter-wave gather: lane = 16*j4 + q; quarter j4 owns edge slot, lane loads
// float4 features [4q..4q+3]. 4 edges per iteration, 1 KB/wave/instruction.
__global__ __launch_bounds__(512, 8) void fused_k(
        const float* __restrict__ x,
        const int* __restrict__ off, const int* __restrict__ boff,
        const int* __restrict__ sorted,
        const float* __restrict__ Ws, const float* __restrict__ bs,
        const float* __restrict__ Wn, const float* __restrict__ bn,
        float* __restrict__ out, int N) {
    __shared__ float sWs[D][D + 1];   // stride 65 -> 2-way bank alias = free
    __shared__ float sWn[D][D + 1];
    __shared__ float sx[NPB][D];
    __shared__ float sm[NPB][D];

    int t = threadIdx.x;
    for (int i = t; i < D * D; i += 512) {
        sWs[i >> 6][i & 63] = Ws[i];
        sWn[i >> 6][i & 63] = Wn[i];
    }

    int w = t >> 6;       // wave id within block
    int f = t & 63;       // lane
    int q = f & 15;       // float4 chunk within row (features 4q..4q+3)
    int j4 = f >> 4;      // edge slot within a group of 4
    int n = blockIdx.x * NPB + w;
    if (n < N) {
        int a = off[n] + boff[n >> 8];
        int b = off[n + 1] + boff[(n + 1) >> 8];
        float4 acc = make_float4(0.f, 0.f, 0.f, 0.f);
        for (int base = a; base < b; base += 64) {
            int rem = b - base;
            int cl = (f < rem) ? sorted[base + f] : 0;   // coalesced idx load
            int m = rem < 64 ? rem : 64;
            for (int jj = 0; jj < m; jj += 4) {
                int slot = jj + j4;
                int c = __shfl(cl, slot);
                if (slot < m) {
                    float4 v = *(const float4*)&x[c * D + 4 * q];
                    acc.x += v.x; acc.y += v.y; acc.z += v.z; acc.w += v.w;
                }
            }
        }
        // reduce across the 4 quarter-waves (xor 16, 32)
        #pragma unroll
        for (int o = 16; o < 64; o <<= 1) {
            acc.x += __shfl_xor(acc.x, o);
            acc.y += __shfl_xor(acc.y, o);
            acc.z += __shfl_xor(acc.z, o);
            acc.w += __shfl_xor(acc.w, o);
        }
        int deg = b - a;
        float dinv = (deg > 0) ? 1.0f / (float)deg : 0.0f;
        if (j4 == 0) {      // lanes 0..15 write the mean row as float4
            float4 mv = make_float4(acc.x * dinv, acc.y * dinv,
                                    acc.z * dinv, acc.w * dinv);
            *(float4*)&sm[w][4 * q] = mv;
        }
        sx[w][f] = x[n * D + f];
    }
    __syncthreads();
    if (n >= N) return;

    float acco = bs[f] + bn[f];
#pragma unroll
    for (int k = 0; k < D; ++k) {
        acco += sWs[f][k] * sx[w][k] + sWn[f][k] * sm[w][k];
    }
    out[n * D + f] = acco;
}

extern "C" void kernel_launch(void* const* d_in, const int* in_sizes, int n_in,
                              void* d_out, int out_size, void* d_ws, size_t ws_size,
                              hipStream_t stream) {
    const float* x  = (const float*)d_in[0];
    const void*  ei = d_in[1];
    const float* Ws = (const float*)d_in[2];
    const float* bs = (const float*)d_in[3];
    const float* Wn = (const float*)d_in[4];
    const float* bn = (const float*)d_in[5];

    int N = in_sizes[0] / D;
    int E = in_sizes[1] / 2;
    int NB = (N + 255) / 256;   // 196 for N=50000; must be <= 256

    int* cnt    = (int*)d_ws;
    int* cursor = cnt + N;
    int* off    = cursor + N;
    int* bsum   = off + N + 1;
    int* boff   = bsum + NB;
    int* sorted = boff + NB;
    int* flag   = sorted + E;

    // zero cnt + cursor
    hipMemsetAsync(d_ws, 0, (size_t)2 * N * sizeof(int), stream);

    detect_k<<<1, 64, 0, stream>>>((const long long*)ei, flag, N);

    int eb = (E + 255) / 256;
    hist_k<<<eb, 256, 0, stream>>>(ei, flag, cnt, E);
    scan1_k<<<NB, 256, 0, stream>>>(cnt, off, bsum, N);
    scan2_k<<<1, 256, 0, stream>>>(bsum, boff, NB);
    scatter_edges_k<<<eb, 256, 0, stream>>>(ei, flag, off, boff, cursor, sorted, E);

    fused_k<<<(N + NPB - 1) / NPB, 512, 0, stream>>>(x, off, boff, sorted,
                                                     Ws, bs, Wn, bn,
                                                     (float*)d_out, N);
}